// Round 6
// baseline (241.765 us; speedup 1.0000x reference)
//
#include <hip/hip_runtime.h>

#define DIM 2048

typedef unsigned int uint2v __attribute__((ext_vector_type(2)));

// Exact sign flip: signs are +/-1 int32; -1 has the int sign bit set.
__device__ __forceinline__ float4 sign_flip(float4 v, uint4 s) {
  float4 r;
  r.x = __uint_as_float(__float_as_uint(v.x) ^ (s.x & 0x80000000u));
  r.y = __uint_as_float(__float_as_uint(v.y) ^ (s.y & 0x80000000u));
  r.z = __uint_as_float(__float_as_uint(v.z) ^ (s.z & 0x80000000u));
  r.w = __uint_as_float(__float_as_uint(v.w) ^ (s.w & 0x80000000u));
  return r;
}

#define BFLY(a, b) { float _t = (a); (a) = _t + (b); (b) = _t - (b); }

__device__ __forceinline__ void bf4_pair(float4 &a, float4 &b) {
  BFLY(a.x, b.x); BFLY(a.y, b.y); BFLY(a.z, b.z); BFLY(a.w, b.w);
}

// Butterfly element-index bits 0 and 1 (within the float4 components).
__device__ __forceinline__ void bf_comps(float4 &a) {
  BFLY(a.x, a.y); BFLY(a.z, a.w);   // bit 0
  BFLY(a.x, a.z); BFLY(a.y, a.w);   // bit 1
}

// Butterfly all 3 bits of the 8-register index (strides 1,2,4).
__device__ __forceinline__ void bf_oct(float4 v[8]) {
  bf4_pair(v[0], v[1]); bf4_pair(v[2], v[3]);
  bf4_pair(v[4], v[5]); bf4_pair(v[6], v[7]);
  bf4_pair(v[0], v[2]); bf4_pair(v[1], v[3]);
  bf4_pair(v[4], v[6]); bf4_pair(v[5], v[7]);
  bf4_pair(v[0], v[4]); bf4_pair(v[1], v[5]);
  bf4_pair(v[2], v[6]); bf4_pair(v[3], v[7]);
}

// Butterfly only reg-index bits 0,1 (strides 1,2) — used for the two
// element bits that the LDS exchange parks in the low reg-index bits.
__device__ __forceinline__ void bf_oct12(float4 v[8]) {
  bf4_pair(v[0], v[1]); bf4_pair(v[2], v[3]);
  bf4_pair(v[4], v[5]); bf4_pair(v[6], v[7]);
  bf4_pair(v[0], v[2]); bf4_pair(v[1], v[3]);
  bf4_pair(v[4], v[6]); bf4_pair(v[5], v[7]);
}

// Cross-lane butterfly on lane bit 0 / 1 via DPP quad_perm (VALU rate).
// 0xB1 = [1,0,3,2] (xor1), 0x4E = [2,3,0,1] (xor2).
template <int CTRL>
__device__ __forceinline__ float dpp_mov(float x) {
  return __int_as_float(
      __builtin_amdgcn_mov_dpp(__float_as_int(x), CTRL, 0xF, 0xF, true));
}

template <int CTRL>
__device__ __forceinline__ void dpp_stage(float4 v[8], float sgn) {
  #pragma unroll
  for (int i = 0; i < 8; ++i) {
    float px = dpp_mov<CTRL>(v[i].x);
    float py = dpp_mov<CTRL>(v[i].y);
    float pz = dpp_mov<CTRL>(v[i].z);
    float pw = dpp_mov<CTRL>(v[i].w);
    // lane with bit clear: x + partner ; lane with bit set: partner - x
    v[i].x = fmaf(sgn, v[i].x, px);
    v[i].y = fmaf(sgn, v[i].y, py);
    v[i].z = fmaf(sgn, v[i].z, pz);
    v[i].w = fmaf(sgn, v[i].w, pw);
  }
}

// Cross-lane butterfly on lane bit 4 via v_permlane16_swap_b32 (VALU rate,
// gfx950). With both operands = x: r[0] = x[lane & ~16], r[1] = x[lane|16]
// (odd 16-rows of dst swap with even 16-rows of src — same duplication
// idiom as the harness-verified permlane32_swap below).
__device__ __forceinline__ float pl16_bfly(float x, float sgn) {
  uint2v r = __builtin_amdgcn_permlane16_swap(
      __float_as_uint(x), __float_as_uint(x), false, false);
  return fmaf(sgn, __uint_as_float(r[1]), __uint_as_float(r[0]));
}

__device__ __forceinline__ void pl16_stage(float4 v[8], float sgn) {
  #pragma unroll
  for (int i = 0; i < 8; ++i) {
    v[i].x = pl16_bfly(v[i].x, sgn);
    v[i].y = pl16_bfly(v[i].y, sgn);
    v[i].z = pl16_bfly(v[i].z, sgn);
    v[i].w = pl16_bfly(v[i].w, sgn);
  }
}

// Cross-lane butterfly on lane bit 5 via v_permlane32_swap_b32 (VALU rate).
// Verified on-harness in a previous round: r[0]=x[lane&~32], r[1]=x[lane|32].
__device__ __forceinline__ float pl32_bfly(float x, float sgn) {
  uint2v r = __builtin_amdgcn_permlane32_swap(
      __float_as_uint(x), __float_as_uint(x), false, false);
  return fmaf(sgn, __uint_as_float(r[1]), __uint_as_float(r[0]));
}

__device__ __forceinline__ void pl32_stage(float4 v[8], float sgn) {
  #pragma unroll
  for (int i = 0; i < 8; ++i) {
    v[i].x = pl32_bfly(v[i].x, sgn);
    v[i].y = pl32_bfly(v[i].y, sgn);
    v[i].z = pl32_bfly(v[i].z, sgn);
    v[i].w = pl32_bfly(v[i].w, sgn);
  }
}

// Wave-local LDS ordering: the LDS slice is per-wave private, so no
// workgroup barrier is needed. DS ops from one wave are processed in
// order; this drains them and stops compiler reordering across it.
__device__ __forceinline__ void lds_fence() {
  asm volatile("s_waitcnt lgkmcnt(0)" ::: "memory");
}

// Block exchange: element bits [4,5] (lane bits 2,3) <-> [8,9] (reg bits
// 0,1). Involution — applying it twice restores the layout. Done in two
// reg-halves {0..3},{4..7} (each closed under the exchange) through a
// 4 KiB per-wave LDS window: 8 b128 writes + 8 b128 reads per call.
// Float4-index XOR swizzle (^4 keyed to the low bit of the writing reg)
// keeps both the write and read phases at the contiguous-pattern bank
// spread (2 lanes/bank per 16-lane phase — free per m136).
__device__ __forceinline__ void xchg(float4* __restrict__ W, float4 v[8],
                                     int lane) {
  const int m  = (lane >> 2) & 3;     // source reg-within-half
  const int ls = lane & ~12;          // lane with bits 2,3 cleared
  #pragma unroll
  for (int half = 0; half < 2; ++half) {
    const int cs = half * 4;
    #pragma unroll
    for (int c2 = 0; c2 < 4; ++c2)
      W[c2 * 64 + (lane ^ ((c2 & 1) << 2))] = v[cs + c2];
    lds_fence();
    #pragma unroll
    for (int c2 = 0; c2 < 4; ++c2)
      v[cs + c2] = W[m * 64 + ((ls | (c2 << 2)) ^ ((m & 1) << 2))];
    lds_fence();   // drain reads before the slice is overwritten again
  }
}

// One wave per 2048-float row. Natural layout N: e = c*256 + lane*4 + r.
//   e0,e1: comps (VALU) | e2,e3: DPP (VALU) | e6: pl16 | e7: pl32 (VALU)
//   e8,e9,e10: regs (VALU) | e4,e5: lane bits 2,3 — the ONLY bits needing
//   data movement, handled by one b128 LDS block-exchange per pass.
// Transposed layout T (after xchg): e4,e5 sit at reg bits 0,1; e8,e9 sit
// at lane bits 2,3; everything else unchanged. Pass 2 runs entirely in T
// (signs re-addressed), and the second xchg restores N for the store.
__global__ __launch_bounds__(256) void srht2_kernel(
    const float* __restrict__ x, const int* __restrict__ signs,
    float* __restrict__ out, int nrows) {
  __shared__ __align__(16) float4 lds[4][256];   // 4 KiB per wave
  const int lane = threadIdx.x & 63;
  const int wv   = threadIdx.x >> 6;
  const int row  = blockIdx.x * 4 + wv;
  if (row >= nrows) return;

  float4* __restrict__ W = lds[wv];

  const float sgn1  = (lane & 1)  ? -1.0f : 1.0f;
  const float sgn2  = (lane & 2)  ? -1.0f : 1.0f;
  const float sgn16 = (lane & 16) ? -1.0f : 1.0f;
  const float sgn32 = (lane & 32) ? -1.0f : 1.0f;

  const float4* __restrict__ xr = (const float4*)(x + (size_t)row * DIM);
  const uint4*  __restrict__ s0 = (const uint4*)signs;
  const uint4*  __restrict__ s1 = (const uint4*)(signs + DIM);

  float4 v[8];
  #pragma unroll
  for (int c = 0; c < 8; ++c) v[c] = xr[c * 64 + lane];

  // ---- pass 1 (layout N): sign flip + 9 VALU bits ----
  #pragma unroll
  for (int c = 0; c < 8; ++c) v[c] = sign_flip(v[c], s0[c * 64 + lane]);
  #pragma unroll
  for (int c = 0; c < 8; ++c) bf_comps(v[c]);   // e0,e1
  dpp_stage<0xB1>(v, sgn1);                     // e2
  dpp_stage<0x4E>(v, sgn2);                     // e3
  pl16_stage(v, sgn16);                         // e6
  pl32_stage(v, sgn32);                         // e7
  bf_oct(v);                                    // e8,e9,e10

  xchg(W, v, lane);                             // N -> T
  bf_oct12(v);                                  // e4,e5 (now reg bits 0,1)

  // ---- pass 2 (layout T): sign flip in T addressing + 9 VALU bits ----
  // uint4 index of thread's c-th fragment in T:
  //   (lane&3) + 4*(c&3) + 16*(lane>>4) + 64*((lane>>2)&3) + 256*(c>>2)
  const int sb = (lane & 3) | ((lane >> 4) << 4) | (((lane >> 2) & 3) << 6);
  #pragma unroll
  for (int c = 0; c < 8; ++c)
    v[c] = sign_flip(v[c], s1[sb + ((c & 3) << 2) + ((c >> 2) << 8)]);
  #pragma unroll
  for (int c = 0; c < 8; ++c) bf_comps(v[c]);   // e0,e1
  dpp_stage<0xB1>(v, sgn1);                     // e2
  dpp_stage<0x4E>(v, sgn2);                     // e3
  pl16_stage(v, sgn16);                         // e6
  pl32_stage(v, sgn32);                         // e7
  bf_oct(v);                                    // e4,e5 (str 1,2) + e10 (str 4)

  xchg(W, v, lane);                             // T -> N
  bf_oct12(v);                                  // e8,e9 (reg bits 0,1 in N)

  // ---- scale (exact pow2) and naturally coalesced store ----
  const float sc = 1.0f / 2048.0f;
  float4* __restrict__ orow = (float4*)(out + (size_t)row * DIM);
  #pragma unroll
  for (int c = 0; c < 8; ++c) {
    float4 t = v[c];
    t.x *= sc; t.y *= sc; t.z *= sc; t.w *= sc;
    orow[c * 64 + lane] = t;
  }
}

extern "C" void kernel_launch(void* const* d_in, const int* in_sizes, int n_in,
                              void* d_out, int out_size, void* d_ws, size_t ws_size,
                              hipStream_t stream) {
  const float* x     = (const float*)d_in[0];
  const int*   signs = (const int*)d_in[1];
  float*       out   = (float*)d_out;
  const int nrows   = in_sizes[0] / DIM;   // 16384
  const int nblocks = nrows / 4;           // 4 waves (rows) per block
  hipLaunchKernelGGL(srht2_kernel, dim3(nblocks), dim3(256), 0, stream,
                     x, signs, out, nrows);
}